// Round 1
// baseline (575.484 us; speedup 1.0000x reference)
//
#include <hip/hip_runtime.h>

// MS-Deformable Attention, MI355X gfx950.
// Pipeline: prep(weights->bf16,[N][K]) ; v=value@Wv (bf16 MFMA, out bf16)
//           p=query@[Woff|Wattn] (bf16 MFMA, out fp32, N padded to 128)
//           sampling (bilinear gather from bf16 v, out bf16)
//           out = samp@Wo + b + query (bf16 MFMA, fp32 out)
// Constants from reference: BS=2, NQ=40000, EMBED=256, HEADS=8, LEVELS=1,
// POINTS=4, HEAD_DIM=32, SPATIAL=(200,200), NV=40000.

typedef float  f4  __attribute__((ext_vector_type(4)));
typedef float  fx4 __attribute__((ext_vector_type(4)));
typedef short  s8  __attribute__((ext_vector_type(8)));

#define M_TOT   80000      // BS*NQ = BS*NV
#define KDIM    256
#define NVPIX   40000
#define GH      200
#define GW      200

__device__ __forceinline__ short f2bf(float f) {
  union { float f; unsigned u; } v; v.f = f;
  unsigned r = v.u + 0x7fffu + ((v.u >> 16) & 1u);   // round-to-nearest-even
  return (short)(r >> 16);
}
__device__ __forceinline__ float bf2f(unsigned short h) {
  union { unsigned u; float f; } v; v.u = ((unsigned)h) << 16; return v.f;
}

// ---------------------------------------------------------------- prep ----
// Transpose+convert weights to bf16 [N][K]; build padded proj weight (rows
// 0..63 = W_off cols, 64..95 = W_attn cols, 96..127 = zero) and its bias.
__global__ void prep_k(const float* __restrict__ Wv, const float* __restrict__ Wo,
                       const float* __restrict__ Woff, const float* __restrict__ Wattn,
                       const float* __restrict__ boff, const float* __restrict__ battn,
                       unsigned short* __restrict__ Wv_t, unsigned short* __restrict__ Wo_t,
                       unsigned short* __restrict__ Wp_t, float* __restrict__ bp)
{
  int i = blockIdx.x * 256 + threadIdx.x;
  if (i < 65536) {
    int n = i >> 8, k = i & 255;
    Wv_t[i] = (unsigned short)f2bf(Wv[k * 256 + n]);
  } else if (i < 131072) {
    int j = i - 65536; int n = j >> 8, k = j & 255;
    Wo_t[j] = (unsigned short)f2bf(Wo[k * 256 + n]);
  } else if (i < 163840) {
    int j = i - 131072; int n = j >> 8, k = j & 255;
    float val = (n < 64) ? Woff[k * 64 + n] : ((n < 96) ? Wattn[k * 32 + (n - 64)] : 0.f);
    Wp_t[j] = (unsigned short)f2bf(val);
  } else if (i < 163968) {
    int j = i - 163840;
    bp[j] = (j < 64) ? boff[j] : ((j < 96) ? battn[j - 64] : 0.f);
  }
}

// ---------------------------------------------------------------- GEMM ----
// C[M,N] = A[M,K=256] * B^T (Bt is [N][K] bf16) + bias (+ resid) ; 128x128
// tile, 4 waves, each wave a 64x64 quadrant of 4x4 16x16x32 bf16 MFMAs.
// LDS rows padded to 40 shorts (80B) -> only 2-way bank aliasing on b128 reads.
template<int ABF, int CBF, int RES>
__global__ __launch_bounds__(256)
void gemm_k(const void* __restrict__ Ap, const unsigned short* __restrict__ Bt,
            const float* __restrict__ bias, const float* __restrict__ resid,
            void* __restrict__ Cp, int N)
{
  __shared__ short As[128 * 40];
  __shared__ short Bs[128 * 40];
  const int t  = threadIdx.x;
  const int m0 = blockIdx.x * 128;
  const int n0 = blockIdx.y * 128;
  const int sr = t >> 1;             // staging row 0..127
  const int sk = (t & 1) * 16;       // staging k-offset 0/16
  const int lane = t & 63;
  const int w  = t >> 6;
  const int wm = (w >> 1) * 64;
  const int wn = (w & 1) * 64;
  const int fr = lane & 15;
  const int quad = lane >> 4;

  fx4 acc[4][4];
  #pragma unroll
  for (int i = 0; i < 4; i++)
    #pragma unroll
    for (int j = 0; j < 4; j++) { fx4 z = {0.f, 0.f, 0.f, 0.f}; acc[i][j] = z; }

  for (int k0 = 0; k0 < KDIM; k0 += 32) {
    __syncthreads();
    if (ABF) {
      const unsigned short* src = (const unsigned short*)Ap + (size_t)(m0 + sr) * KDIM + k0 + sk;
      s8 a0 = *(const s8*)(src);
      s8 a1 = *(const s8*)(src + 8);
      *(s8*)(&As[sr * 40 + sk])     = a0;
      *(s8*)(&As[sr * 40 + sk + 8]) = a1;
    } else {
      const float* src = (const float*)Ap + (size_t)(m0 + sr) * KDIM + k0 + sk;
      f4 f0 = *(const f4*)(src);
      f4 f1 = *(const f4*)(src + 4);
      f4 f2 = *(const f4*)(src + 8);
      f4 f3 = *(const f4*)(src + 12);
      s8 a0, a1;
      #pragma unroll
      for (int i = 0; i < 4; i++) {
        a0[i]     = f2bf(f0[i]);
        a0[i + 4] = f2bf(f1[i]);
        a1[i]     = f2bf(f2[i]);
        a1[i + 4] = f2bf(f3[i]);
      }
      *(s8*)(&As[sr * 40 + sk])     = a0;
      *(s8*)(&As[sr * 40 + sk + 8]) = a1;
    }
    {
      const unsigned short* src = Bt + (size_t)(n0 + sr) * KDIM + k0 + sk;
      s8 b0 = *(const s8*)(src);
      s8 b1 = *(const s8*)(src + 8);
      *(s8*)(&Bs[sr * 40 + sk])     = b0;
      *(s8*)(&Bs[sr * 40 + sk + 8]) = b1;
    }
    __syncthreads();

    s8 afr[4], bfr[4];
    #pragma unroll
    for (int i = 0; i < 4; i++) afr[i] = *(const s8*)(&As[(wm + i * 16 + fr) * 40 + quad * 8]);
    #pragma unroll
    for (int i = 0; i < 4; i++) bfr[i] = *(const s8*)(&Bs[(wn + i * 16 + fr) * 40 + quad * 8]);
    #pragma unroll
    for (int i = 0; i < 4; i++)
      #pragma unroll
      for (int j = 0; j < 4; j++)
        acc[i][j] = __builtin_amdgcn_mfma_f32_16x16x32_bf16(afr[i], bfr[j], acc[i][j], 0, 0, 0);
  }

  // Epilogue: C/D layout col=lane&15, row=quad*4+reg (verified m89/m91).
  #pragma unroll
  for (int i = 0; i < 4; i++) {
    const int mbase = m0 + wm + i * 16 + quad * 4;
    #pragma unroll
    for (int j = 0; j < 4; j++) {
      const int n = n0 + wn + j * 16 + fr;
      const float bn = bias[n];
      #pragma unroll
      for (int r = 0; r < 4; r++) {
        const size_t m = (size_t)(mbase + r);
        float v = acc[i][j][r] + bn;
        if (RES) v += resid[m * (size_t)N + n];
        if (CBF) ((unsigned short*)Cp)[m * (size_t)N + n] = (unsigned short)f2bf(v);
        else     ((float*)Cp)[m * (size_t)N + n] = v;
      }
    }
  }
}

// ------------------------------------------------------------- sampling ----
// One block per query. Thread t: head h=t>>5, dim d=t&31. Reads the 96
// projection outputs + ref point via LDS, per-head softmax over 4 points,
// bilinear-gathers 4 pts x 4 corners from bf16 v [b][pix][h*32+d].
__global__ __launch_bounds__(256)
void sample_k(const unsigned short* __restrict__ v, const float* __restrict__ p,
              const float* __restrict__ ref, unsigned short* __restrict__ o)
{
  const int q = blockIdx.x;          // 0..79999 (b*NQ + qi)
  const int b = q / 40000;
  const int t = threadIdx.x;
  const int h = t >> 5;
  const int d = t & 31;
  __shared__ float sp[98];
  if (t < 96) sp[t] = p[(size_t)q * 128 + t];
  if (t >= 96 && t < 98) sp[t] = ref[(size_t)q * 2 + (t - 96)];
  __syncthreads();

  const float lg0 = sp[64 + h * 4 + 0], lg1 = sp[64 + h * 4 + 1];
  const float lg2 = sp[64 + h * 4 + 2], lg3 = sp[64 + h * 4 + 3];
  const float mx = fmaxf(fmaxf(lg0, lg1), fmaxf(lg2, lg3));
  const float e0 = __expf(lg0 - mx), e1 = __expf(lg1 - mx);
  const float e2 = __expf(lg2 - mx), e3 = __expf(lg3 - mx);
  const float inv = 1.f / (e0 + e1 + e2 + e3);
  const float aws[4] = {e0 * inv, e1 * inv, e2 * inv, e3 * inv};
  const float rx = sp[96], ry = sp[97];

  const unsigned short* vb = v + (size_t)b * NVPIX * 256 + h * 32 + d;
  float acc = 0.f;
  #pragma unroll
  for (int pt = 0; pt < 4; ++pt) {
    const float ox = sp[h * 8 + pt * 2], oy = sp[h * 8 + pt * 2 + 1];
    // px = loc_x*W - 0.5 with loc_x = rx + ox/W  ->  rx*W + ox - 0.5
    const float px = rx * 200.f + ox - 0.5f;
    const float py = ry * 200.f + oy - 0.5f;
    const float x0f = floorf(px), y0f = floorf(py);
    const int ix = (int)x0f, iy = (int)y0f;
    const float fx = px - x0f, fy = py - y0f;
    const float a = aws[pt];
    const float w00 = a * (1.f - fx) * (1.f - fy);
    const float w01 = a * fx * (1.f - fy);
    const float w10 = a * (1.f - fx) * fy;
    const float w11 = a * fx * fy;
    const bool x0ok = (ix >= 0) && (ix < GW);
    const bool x1ok = (ix + 1 >= 0) && (ix + 1 < GW);
    const bool y0ok = (iy >= 0) && (iy < GH);
    const bool y1ok = (iy + 1 >= 0) && (iy + 1 < GH);
    const unsigned short* row0 = vb + (long)iy * GW * 256;
    const unsigned short* row1 = row0 + GW * 256;
    if (y0ok && x0ok) acc += w00 * bf2f(row0[(long)ix * 256]);
    if (y0ok && x1ok) acc += w01 * bf2f(row0[(long)(ix + 1) * 256]);
    if (y1ok && x0ok) acc += w10 * bf2f(row1[(long)ix * 256]);
    if (y1ok && x1ok) acc += w11 * bf2f(row1[(long)(ix + 1) * 256]);
  }
  o[(size_t)q * 256 + t] = (unsigned short)f2bf(acc);
}

// --------------------------------------------------------------- launch ----
extern "C" void kernel_launch(void* const* d_in, const int* in_sizes, int n_in,
                              void* d_out, int out_size, void* d_ws, size_t ws_size,
                              hipStream_t stream)
{
  const float* query = (const float*)d_in[0];
  const float* value = (const float*)d_in[1];
  const float* refp  = (const float*)d_in[2];
  // d_in[3] spatial_shapes: compile-time (200,200)
  const float* Wv    = (const float*)d_in[4];
  const float* bv    = (const float*)d_in[5];
  const float* Woff  = (const float*)d_in[6];
  const float* boff  = (const float*)d_in[7];
  const float* Wattn = (const float*)d_in[8];
  const float* battn = (const float*)d_in[9];
  const float* Wo    = (const float*)d_in[10];
  const float* bo    = (const float*)d_in[11];

  char* ws = (char*)d_ws;
  unsigned short* ws_v = (unsigned short*)ws;                  // 80000*256 bf16 = 40.96 MB
  float*          ws_p = (float*)(ws + 40960000);              // 80000*128 f32  = 40.96 MB
  unsigned short* ws_o = (unsigned short*)(ws + 81920000);     // 80000*256 bf16 = 40.96 MB
  unsigned short* Wv_t = (unsigned short*)(ws + 122880000);    // 256*256 bf16
  unsigned short* Wo_t = Wv_t + 65536;                         // 256*256 bf16
  unsigned short* Wp_t = Wo_t + 65536;                         // 128*256 bf16
  float*          bp   = (float*)(Wp_t + 32768);               // 128 f32

  hipLaunchKernelGGL(prep_k, dim3(641), dim3(256), 0, stream,
                     Wv, Wo, Woff, Wattn, boff, battn, Wv_t, Wo_t, Wp_t, bp);
  // v = value @ Wv + bv  -> bf16
  hipLaunchKernelGGL((gemm_k<0, 1, 0>), dim3(625, 2), dim3(256), 0, stream,
                     (const void*)value, Wv_t, bv, (const float*)nullptr, (void*)ws_v, 256);
  // p = query @ [Woff|Wattn|0] + bp -> f32 (stride 128)
  hipLaunchKernelGGL((gemm_k<0, 0, 0>), dim3(625, 1), dim3(256), 0, stream,
                     (const void*)query, Wp_t, bp, (const float*)nullptr, (void*)ws_p, 128);
  // sampling
  hipLaunchKernelGGL(sample_k, dim3(80000), dim3(256), 0, stream,
                     ws_v, ws_p, refp, ws_o);
  // out = samp @ Wo + bo + query -> f32
  hipLaunchKernelGGL((gemm_k<1, 0, 1>), dim3(625, 2), dim3(256), 0, stream,
                     (const void*)ws_o, Wo_t, bo, query, (void*)d_out, 256);
}

// Round 2
// 408.013 us; speedup vs baseline: 1.4105x; 1.4105x over previous
//
#include <hip/hip_runtime.h>

// MS-Deformable Attention, MI355X gfx950.
// Pipeline: prep(weights->bf16,[N][K]) ; v=value@Wv (bf16 MFMA, out bf16)
//           p=query@[Woff|Wattn] (bf16 MFMA, out fp32, N padded to 128)
//           sampling (bilinear gather from bf16 v, out bf16)
//           out = samp@Wo + b + query (bf16 MFMA, fp32 out)
// Constants from reference: BS=2, NQ=40000, EMBED=256, HEADS=8, LEVELS=1,
// POINTS=4, HEAD_DIM=32, SPATIAL=(200,200), NV=40000.

typedef float  f4  __attribute__((ext_vector_type(4)));
typedef float  fx4 __attribute__((ext_vector_type(4)));
typedef short  s8  __attribute__((ext_vector_type(8)));

#define M_TOT   80000      // BS*NQ = BS*NV
#define KDIM    256
#define NVPIX   40000
#define GH      200
#define GW      200

__device__ __forceinline__ short f2bf(float f) {
  union { float f; unsigned u; } v; v.f = f;
  unsigned r = v.u + 0x7fffu + ((v.u >> 16) & 1u);   // round-to-nearest-even
  return (short)(r >> 16);
}
__device__ __forceinline__ float bf2f(unsigned short h) {
  union { unsigned u; float f; } v; v.u = ((unsigned)h) << 16; return v.f;
}

// ---------------------------------------------------------------- prep ----
__global__ void prep_k(const float* __restrict__ Wv, const float* __restrict__ Wo,
                       const float* __restrict__ Woff, const float* __restrict__ Wattn,
                       const float* __restrict__ boff, const float* __restrict__ battn,
                       unsigned short* __restrict__ Wv_t, unsigned short* __restrict__ Wo_t,
                       unsigned short* __restrict__ Wp_t, float* __restrict__ bp)
{
  int i = blockIdx.x * 256 + threadIdx.x;
  if (i < 65536) {
    int n = i >> 8, k = i & 255;
    Wv_t[i] = (unsigned short)f2bf(Wv[k * 256 + n]);
  } else if (i < 131072) {
    int j = i - 65536; int n = j >> 8, k = j & 255;
    Wo_t[j] = (unsigned short)f2bf(Wo[k * 256 + n]);
  } else if (i < 163840) {
    int j = i - 131072; int n = j >> 8, k = j & 255;
    float val = (n < 64) ? Woff[k * 64 + n] : ((n < 96) ? Wattn[k * 32 + (n - 64)] : 0.f);
    Wp_t[j] = (unsigned short)f2bf(val);
  } else if (i < 163968) {
    int j = i - 163840;
    bp[j] = (j < 64) ? boff[j] : ((j < 96) ? battn[j - 64] : 0.f);
  }
}

// ---------------------------------------------------------------- GEMM ----
// C[M,N] = A[M,K=256] * B^T (Bt is [N][K] bf16) + bias (+ resid) ; 128x128
// tile, 4 waves, each wave a 64x64 quadrant of 4x4 16x16x32 bf16 MFMAs.
template<int ABF, int CBF, int RES>
__global__ __launch_bounds__(256)
void gemm_k(const void* __restrict__ Ap, const unsigned short* __restrict__ Bt,
            const float* __restrict__ bias, const float* __restrict__ resid,
            void* __restrict__ Cp, int N)
{
  __shared__ short As[128 * 40];
  __shared__ short Bs[128 * 40];
  const int t  = threadIdx.x;
  const int m0 = blockIdx.x * 128;
  const int n0 = blockIdx.y * 128;
  const int sr = t >> 1;             // staging row 0..127
  const int sk = (t & 1) * 16;       // staging k-offset 0/16
  const int lane = t & 63;
  const int w  = t >> 6;
  const int wm = (w >> 1) * 64;
  const int wn = (w & 1) * 64;
  const int fr = lane & 15;
  const int quad = lane >> 4;

  fx4 acc[4][4];
  #pragma unroll
  for (int i = 0; i < 4; i++)
    #pragma unroll
    for (int j = 0; j < 4; j++) { fx4 z = {0.f, 0.f, 0.f, 0.f}; acc[i][j] = z; }

  for (int k0 = 0; k0 < KDIM; k0 += 32) {
    __syncthreads();
    if (ABF) {
      const unsigned short* src = (const unsigned short*)Ap + (size_t)(m0 + sr) * KDIM + k0 + sk;
      s8 a0 = *(const s8*)(src);
      s8 a1 = *(const s8*)(src + 8);
      *(s8*)(&As[sr * 40 + sk])     = a0;
      *(s8*)(&As[sr * 40 + sk + 8]) = a1;
    } else {
      const float* src = (const float*)Ap + (size_t)(m0 + sr) * KDIM + k0 + sk;
      f4 f0 = *(const f4*)(src);
      f4 f1 = *(const f4*)(src + 4);
      f4 f2 = *(const f4*)(src + 8);
      f4 f3 = *(const f4*)(src + 12);
      s8 a0, a1;
      #pragma unroll
      for (int i = 0; i < 4; i++) {
        a0[i]     = f2bf(f0[i]);
        a0[i + 4] = f2bf(f1[i]);
        a1[i]     = f2bf(f2[i]);
        a1[i + 4] = f2bf(f3[i]);
      }
      *(s8*)(&As[sr * 40 + sk])     = a0;
      *(s8*)(&As[sr * 40 + sk + 8]) = a1;
    }
    {
      const unsigned short* src = Bt + (size_t)(n0 + sr) * KDIM + k0 + sk;
      s8 b0 = *(const s8*)(src);
      s8 b1 = *(const s8*)(src + 8);
      *(s8*)(&Bs[sr * 40 + sk])     = b0;
      *(s8*)(&Bs[sr * 40 + sk + 8]) = b1;
    }
    __syncthreads();

    s8 afr[4], bfr[4];
    #pragma unroll
    for (int i = 0; i < 4; i++) afr[i] = *(const s8*)(&As[(wm + i * 16 + fr) * 40 + quad * 8]);
    #pragma unroll
    for (int i = 0; i < 4; i++) bfr[i] = *(const s8*)(&Bs[(wn + i * 16 + fr) * 40 + quad * 8]);
    #pragma unroll
    for (int i = 0; i < 4; i++)
      #pragma unroll
      for (int j = 0; j < 4; j++)
        acc[i][j] = __builtin_amdgcn_mfma_f32_16x16x32_bf16(afr[i], bfr[j], acc[i][j], 0, 0, 0);
  }

  // Epilogue: C/D layout col=lane&15, row=quad*4+reg (verified m89/m91).
  #pragma unroll
  for (int i = 0; i < 4; i++) {
    const int mbase = m0 + wm + i * 16 + quad * 4;
    #pragma unroll
    for (int j = 0; j < 4; j++) {
      const int n = n0 + wn + j * 16 + fr;
      const float bn = bias[n];
      #pragma unroll
      for (int r = 0; r < 4; r++) {
        const size_t m = (size_t)(mbase + r);
        float v = acc[i][j][r] + bn;
        if (RES) v += resid[m * (size_t)N + n];
        if (CBF) ((unsigned short*)Cp)[m * (size_t)N + n] = (unsigned short)f2bf(v);
        else     ((float*)Cp)[m * (size_t)N + n] = v;
      }
    }
  }
}

// ------------------------------------------------------------- sampling ----
// 8 queries per block. Thread t: query qi=t>>5, head h=(t>>2)&7, dim-group
// dg=t&3 (8 consecutive dims -> one dwordx4 per corner). Validity folded
// into weights; loads unconditional with clamped indices (no divergence,
// all 16 loads independent -> latency hiding).
__global__ __launch_bounds__(256)
void sample_k(const unsigned short* __restrict__ v, const float* __restrict__ p,
              const float* __restrict__ ref, unsigned short* __restrict__ o)
{
  const int t  = threadIdx.x;
  const int q0 = blockIdx.x * 8;
  __shared__ float sp[8][128];
  __shared__ float sref[16];
  {
    const float* pb = p + (size_t)q0 * 128;
    #pragma unroll
    for (int j = 0; j < 4; j++) {
      int i = t + j * 256;
      sp[i >> 7][i & 127] = pb[i];
    }
    if (t < 16) sref[t] = ref[(size_t)q0 * 2 + t];
  }
  __syncthreads();

  const int qi = t >> 5;
  const int h  = (t >> 2) & 7;
  const int dg = t & 3;
  const int q  = q0 + qi;
  const int b  = (q >= 40000) ? 1 : 0;

  const float lg0 = sp[qi][64 + h * 4 + 0], lg1 = sp[qi][64 + h * 4 + 1];
  const float lg2 = sp[qi][64 + h * 4 + 2], lg3 = sp[qi][64 + h * 4 + 3];
  const float mx = fmaxf(fmaxf(lg0, lg1), fmaxf(lg2, lg3));
  const float e0 = __expf(lg0 - mx), e1 = __expf(lg1 - mx);
  const float e2 = __expf(lg2 - mx), e3 = __expf(lg3 - mx);
  const float inv = 1.f / (e0 + e1 + e2 + e3);
  const float aws[4] = {e0 * inv, e1 * inv, e2 * inv, e3 * inv};
  const float rx = sref[qi * 2], ry = sref[qi * 2 + 1];

  const unsigned short* vb = v + (size_t)b * NVPIX * 256;
  const int cbase = h * 32 + dg * 8;

  float acc[8];
  #pragma unroll
  for (int e = 0; e < 8; e++) acc[e] = 0.f;

  #pragma unroll
  for (int pt = 0; pt < 4; ++pt) {
    const float ox = sp[qi][h * 8 + pt * 2], oy = sp[qi][h * 8 + pt * 2 + 1];
    // px = loc_x*W - 0.5 with loc_x = rx + ox/W  ->  rx*W + ox - 0.5
    const float px = rx * 200.f + ox - 0.5f;
    const float py = ry * 200.f + oy - 0.5f;
    const float x0f = floorf(px), y0f = floorf(py);
    const int ix = (int)x0f, iy = (int)y0f;
    const float fx = px - x0f, fy = py - y0f;
    const float a = aws[pt];
    const float vx0 = (ix >= 0 && ix < GW) ? 1.f : 0.f;
    const float vx1 = (ix + 1 >= 0 && ix + 1 < GW) ? 1.f : 0.f;
    const float vy0 = (iy >= 0 && iy < GH) ? 1.f : 0.f;
    const float vy1 = (iy + 1 >= 0 && iy + 1 < GH) ? 1.f : 0.f;
    const float w00 = a * (1.f - fx) * (1.f - fy) * vx0 * vy0;
    const float w01 = a * fx * (1.f - fy) * vx1 * vy0;
    const float w10 = a * (1.f - fx) * fy * vx0 * vy1;
    const float w11 = a * fx * fy * vx1 * vy1;
    const int ix0c = min(max(ix, 0), GW - 1);
    const int ix1c = min(max(ix + 1, 0), GW - 1);
    const int iy0c = min(max(iy, 0), GH - 1);
    const int iy1c = min(max(iy + 1, 0), GH - 1);
    const int r0 = iy0c * (GW * 256) + cbase;
    const int r1 = iy1c * (GW * 256) + cbase;
    s8 g00 = *(const s8*)(vb + r0 + ix0c * 256);
    s8 g01 = *(const s8*)(vb + r0 + ix1c * 256);
    s8 g10 = *(const s8*)(vb + r1 + ix0c * 256);
    s8 g11 = *(const s8*)(vb + r1 + ix1c * 256);
    #pragma unroll
    for (int e = 0; e < 8; e++) {
      acc[e] += w00 * bf2f((unsigned short)g00[e]) + w01 * bf2f((unsigned short)g01[e])
              + w10 * bf2f((unsigned short)g10[e]) + w11 * bf2f((unsigned short)g11[e]);
    }
  }

  s8 res;
  #pragma unroll
  for (int e = 0; e < 8; e++) res[e] = f2bf(acc[e]);
  *(s8*)(o + (size_t)q * 256 + cbase) = res;
}

// --------------------------------------------------------------- launch ----
extern "C" void kernel_launch(void* const* d_in, const int* in_sizes, int n_in,
                              void* d_out, int out_size, void* d_ws, size_t ws_size,
                              hipStream_t stream)
{
  const float* query = (const float*)d_in[0];
  const float* value = (const float*)d_in[1];
  const float* refp  = (const float*)d_in[2];
  // d_in[3] spatial_shapes: compile-time (200,200)
  const float* Wv    = (const float*)d_in[4];
  const float* bv    = (const float*)d_in[5];
  const float* Woff  = (const float*)d_in[6];
  const float* boff  = (const float*)d_in[7];
  const float* Wattn = (const float*)d_in[8];
  const float* battn = (const float*)d_in[9];
  const float* Wo    = (const float*)d_in[10];
  const float* bo    = (const float*)d_in[11];

  char* ws = (char*)d_ws;
  unsigned short* ws_v = (unsigned short*)ws;                  // 80000*256 bf16 = 40.96 MB
  float*          ws_p = (float*)(ws + 40960000);              // 80000*128 f32  = 40.96 MB
  unsigned short* ws_o = (unsigned short*)(ws + 81920000);     // 80000*256 bf16 = 40.96 MB
  unsigned short* Wv_t = (unsigned short*)(ws + 122880000);    // 256*256 bf16
  unsigned short* Wo_t = Wv_t + 65536;                         // 256*256 bf16
  unsigned short* Wp_t = Wo_t + 65536;                         // 128*256 bf16
  float*          bp   = (float*)(Wp_t + 32768);               // 128 f32

  hipLaunchKernelGGL(prep_k, dim3(641), dim3(256), 0, stream,
                     Wv, Wo, Woff, Wattn, boff, battn, Wv_t, Wo_t, Wp_t, bp);
  // v = value @ Wv + bv  -> bf16
  hipLaunchKernelGGL((gemm_k<0, 1, 0>), dim3(625, 2), dim3(256), 0, stream,
                     (const void*)value, Wv_t, bv, (const float*)nullptr, (void*)ws_v, 256);
  // p = query @ [Woff|Wattn|0] + bp -> f32 (stride 128)
  hipLaunchKernelGGL((gemm_k<0, 0, 0>), dim3(625, 1), dim3(256), 0, stream,
                     (const void*)query, Wp_t, bp, (const float*)nullptr, (void*)ws_p, 128);
  // sampling
  hipLaunchKernelGGL(sample_k, dim3(10000), dim3(256), 0, stream,
                     ws_v, ws_p, refp, ws_o);
  // out = samp @ Wo + bo + query -> f32
  hipLaunchKernelGGL((gemm_k<1, 0, 1>), dim3(625, 2), dim3(256), 0, stream,
                     (const void*)ws_o, Wo_t, bo, query, (void*)d_out, 256);
}

// Round 3
// 353.516 us; speedup vs baseline: 1.6279x; 1.1542x over previous
//
#include <hip/hip_runtime.h>

// MS-Deformable Attention, MI355X gfx950.
// Pipeline: prep(weights->bf16,[N][K]) ; v=value@Wv (bf16 MFMA, out bf16)
//           p=query@[Woff|Wattn] (bf16 MFMA, out fp32, N padded to 128)
//           sampling (bilinear gather from bf16 v, out bf16)
//           out = samp@Wo + b + query (bf16 MFMA, fp32 out)
// R2: gemm was latency-bound (MfmaUtil 3.9%, VALUBusy 3.3%, occ 25%).
//     -> software-pipelined reg prefetch, BK=64 (4 iters), pad 68 (0 conflicts).

typedef float  f4  __attribute__((ext_vector_type(4)));
typedef float  fx4 __attribute__((ext_vector_type(4)));
typedef short  s8  __attribute__((ext_vector_type(8)));
typedef short  s4  __attribute__((ext_vector_type(4)));

#define KDIM    256
#define NVPIX   40000
#define GH      200
#define GW      200
#define LDP     68          // LDS row pitch in shorts: 64 data + 4 pad -> conflict-free

__device__ __forceinline__ short f2bf(float f) {
  union { float f; unsigned u; } v; v.f = f;
  unsigned r = v.u + 0x7fffu + ((v.u >> 16) & 1u);   // round-to-nearest-even
  return (short)(r >> 16);
}
__device__ __forceinline__ float bf2f(unsigned short h) {
  union { unsigned u; float f; } v; v.u = ((unsigned)h) << 16; return v.f;
}

// ---------------------------------------------------------------- prep ----
__global__ void prep_k(const float* __restrict__ Wv, const float* __restrict__ Wo,
                       const float* __restrict__ Woff, const float* __restrict__ Wattn,
                       const float* __restrict__ boff, const float* __restrict__ battn,
                       unsigned short* __restrict__ Wv_t, unsigned short* __restrict__ Wo_t,
                       unsigned short* __restrict__ Wp_t, float* __restrict__ bp)
{
  int i = blockIdx.x * 256 + threadIdx.x;
  if (i < 65536) {
    int n = i >> 8, k = i & 255;
    Wv_t[i] = (unsigned short)f2bf(Wv[k * 256 + n]);
  } else if (i < 131072) {
    int j = i - 65536; int n = j >> 8, k = j & 255;
    Wo_t[j] = (unsigned short)f2bf(Wo[k * 256 + n]);
  } else if (i < 163840) {
    int j = i - 131072; int n = j >> 8, k = j & 255;
    float val = (n < 64) ? Woff[k * 64 + n] : ((n < 96) ? Wattn[k * 32 + (n - 64)] : 0.f);
    Wp_t[j] = (unsigned short)f2bf(val);
  } else if (i < 163968) {
    int j = i - 163840;
    bp[j] = (j < 64) ? boff[j] : ((j < 96) ? battn[j - 64] : 0.f);
  }
}

// ---------------------------------------------------------------- GEMM ----
// C[M,N] = A[M,K=256] * B^T (Bt [N][K] bf16) + bias (+resid). 128x128 tile,
// BK=64 (4 k-iters), 4 waves each doing a 64x64 quadrant of 4x4 16x16x32
// MFMAs (2 k-steps/iter). Register-prefetch pipeline: next tile's global
// loads are issued BEFORE the MFMA section so ~900cyc HBM latency overlaps
// 32 MFMAs + 16 ds_reads; waitcnt lands at next iter's ds_write.
template<int ABF, int CBF, int RES>
__global__ __launch_bounds__(256)
void gemm_k(const void* __restrict__ Ap, const unsigned short* __restrict__ Bt,
            const float* __restrict__ bias, const float* __restrict__ resid,
            void* __restrict__ Cp, int N)
{
  __shared__ short As[128 * LDP];
  __shared__ short Bs[128 * LDP];
  const int t  = threadIdx.x;
  const int m0 = blockIdx.x * 128;
  const int n0 = blockIdx.y * 128;
  const int lane = t & 63;
  const int w  = t >> 6;
  const int wm = (w >> 1) * 64;
  const int wn = (w & 1) * 64;
  const int fr = lane & 15;
  const int quad = lane >> 4;

  fx4 acc[4][4];
  #pragma unroll
  for (int i = 0; i < 4; i++)
    #pragma unroll
    for (int j = 0; j < 4; j++) { fx4 z = {0.f, 0.f, 0.f, 0.f}; acc[i][j] = z; }

  f4 pa[8];    // ABF=0 prefetch: 128x64 f32 tile = 2048 f4, 8 per thread
  s8 pa8[4];   // ABF=1 prefetch: 128x64 bf16 tile = 1024 s8, 4 per thread
  s8 pb[4];    // B prefetch

  auto loadA = [&](int k0) {
    if (ABF) {
      const unsigned short* base = (const unsigned short*)Ap + (size_t)m0 * KDIM + k0;
      #pragma unroll
      for (int j = 0; j < 4; j++) {
        int id = t + j * 256;                   // coalesced
        int row = id >> 3, kp = (id & 7) * 8;
        pa8[j] = *(const s8*)(base + (size_t)row * KDIM + kp);
      }
    } else {
      const float* base = (const float*)Ap + (size_t)m0 * KDIM + k0;
      #pragma unroll
      for (int j = 0; j < 8; j++) {
        int id = t + j * 256;                   // coalesced
        int row = id >> 4, kp = (id & 15) * 4;
        pa[j] = *(const f4*)(base + (size_t)row * KDIM + kp);
      }
    }
  };
  auto loadB = [&](int k0) {
    const unsigned short* base = Bt + (size_t)n0 * KDIM + k0;
    #pragma unroll
    for (int j = 0; j < 4; j++) {
      int id = t + j * 256;
      int row = id >> 3, kp = (id & 7) * 8;
      pb[j] = *(const s8*)(base + (size_t)row * KDIM + kp);
    }
  };
  auto storeAB = [&]() {
    if (ABF) {
      #pragma unroll
      for (int j = 0; j < 4; j++) {
        int id = t + j * 256;
        int row = id >> 3, kp = (id & 7) * 8;
        *(s8*)(&As[row * LDP + kp]) = pa8[j];
      }
    } else {
      #pragma unroll
      for (int j = 0; j < 8; j++) {
        int id = t + j * 256;
        int row = id >> 4, kp = (id & 15) * 4;
        s4 c;
        #pragma unroll
        for (int e = 0; e < 4; e++) c[e] = f2bf(pa[j][e]);
        *(s4*)(&As[row * LDP + kp]) = c;        // ds_write_b64, conflict-free
      }
    }
    #pragma unroll
    for (int j = 0; j < 4; j++) {
      int id = t + j * 256;
      int row = id >> 3, kp = (id & 7) * 8;
      *(s8*)(&Bs[row * LDP + kp]) = pb[j];      // ds_write_b128, conflict-free
    }
  };

  loadA(0); loadB(0);
  #pragma unroll
  for (int it = 0; it < 4; ++it) {
    __syncthreads();            // prev-iter LDS reads complete
    storeAB();
    __syncthreads();
    if (it < 3) { loadA((it + 1) * 64); loadB((it + 1) * 64); }  // prefetch next
    #pragma unroll
    for (int kk = 0; kk < 2; kk++) {
      s8 afr[4], bfr[4];
      #pragma unroll
      for (int i = 0; i < 4; i++)
        afr[i] = *(const s8*)(&As[(wm + i * 16 + fr) * LDP + kk * 32 + quad * 8]);
      #pragma unroll
      for (int i = 0; i < 4; i++)
        bfr[i] = *(const s8*)(&Bs[(wn + i * 16 + fr) * LDP + kk * 32 + quad * 8]);
      #pragma unroll
      for (int i = 0; i < 4; i++)
        #pragma unroll
        for (int j = 0; j < 4; j++)
          acc[i][j] = __builtin_amdgcn_mfma_f32_16x16x32_bf16(afr[i], bfr[j], acc[i][j], 0, 0, 0);
    }
  }

  // Epilogue: C/D layout col=lane&15, row=quad*4+reg (verified m89/m91).
  #pragma unroll
  for (int i = 0; i < 4; i++) {
    const int mbase = m0 + wm + i * 16 + quad * 4;
    #pragma unroll
    for (int j = 0; j < 4; j++) {
      const int n = n0 + wn + j * 16 + fr;
      const float bn = bias[n];
      #pragma unroll
      for (int r = 0; r < 4; r++) {
        const size_t m = (size_t)(mbase + r);
        float v = acc[i][j][r] + bn;
        if (RES) v += resid[m * (size_t)N + n];
        if (CBF) ((unsigned short*)Cp)[m * (size_t)N + n] = (unsigned short)f2bf(v);
        else     ((float*)Cp)[m * (size_t)N + n] = v;
      }
    }
  }
}

// ------------------------------------------------------------- sampling ----
// 8 queries per block. Thread t: query qi=t>>5, head h=(t>>2)&7, dim-group
// dg=t&3 (8 consecutive dims -> one dwordx4 per corner). Validity folded
// into weights; loads unconditional with clamped indices.
__global__ __launch_bounds__(256)
void sample_k(const unsigned short* __restrict__ v, const float* __restrict__ p,
              const float* __restrict__ ref, unsigned short* __restrict__ o)
{
  const int t  = threadIdx.x;
  const int q0 = blockIdx.x * 8;
  __shared__ float sp[8][128];
  __shared__ float sref[16];
  {
    const float* pb = p + (size_t)q0 * 128;
    #pragma unroll
    for (int j = 0; j < 4; j++) {
      int i = t + j * 256;
      sp[i >> 7][i & 127] = pb[i];
    }
    if (t < 16) sref[t] = ref[(size_t)q0 * 2 + t];
  }
  __syncthreads();

  const int qi = t >> 5;
  const int h  = (t >> 2) & 7;
  const int dg = t & 3;
  const int q  = q0 + qi;
  const int b  = (q >= 40000) ? 1 : 0;

  const float lg0 = sp[qi][64 + h * 4 + 0], lg1 = sp[qi][64 + h * 4 + 1];
  const float lg2 = sp[qi][64 + h * 4 + 2], lg3 = sp[qi][64 + h * 4 + 3];
  const float mx = fmaxf(fmaxf(lg0, lg1), fmaxf(lg2, lg3));
  const float e0 = __expf(lg0 - mx), e1 = __expf(lg1 - mx);
  const float e2 = __expf(lg2 - mx), e3 = __expf(lg3 - mx);
  const float inv = 1.f / (e0 + e1 + e2 + e3);
  const float aws[4] = {e0 * inv, e1 * inv, e2 * inv, e3 * inv};
  const float rx = sref[qi * 2], ry = sref[qi * 2 + 1];

  const unsigned short* vb = v + (size_t)b * NVPIX * 256;
  const int cbase = h * 32 + dg * 8;

  float acc[8];
  #pragma unroll
  for (int e = 0; e < 8; e++) acc[e] = 0.f;

  #pragma unroll
  for (int pt = 0; pt < 4; ++pt) {
    const float ox = sp[qi][h * 8 + pt * 2], oy = sp[qi][h * 8 + pt * 2 + 1];
    // px = loc_x*W - 0.5 with loc_x = rx + ox/W  ->  rx*W + ox - 0.5
    const float px = rx * 200.f + ox - 0.5f;
    const float py = ry * 200.f + oy - 0.5f;
    const float x0f = floorf(px), y0f = floorf(py);
    const int ix = (int)x0f, iy = (int)y0f;
    const float fx = px - x0f, fy = py - y0f;
    const float a = aws[pt];
    const float vx0 = (ix >= 0 && ix < GW) ? 1.f : 0.f;
    const float vx1 = (ix + 1 >= 0 && ix + 1 < GW) ? 1.f : 0.f;
    const float vy0 = (iy >= 0 && iy < GH) ? 1.f : 0.f;
    const float vy1 = (iy + 1 >= 0 && iy + 1 < GH) ? 1.f : 0.f;
    const float w00 = a * (1.f - fx) * (1.f - fy) * vx0 * vy0;
    const float w01 = a * fx * (1.f - fy) * vx1 * vy0;
    const float w10 = a * (1.f - fx) * fy * vx0 * vy1;
    const float w11 = a * fx * fy * vx1 * vy1;
    const int ix0c = min(max(ix, 0), GW - 1);
    const int ix1c = min(max(ix + 1, 0), GW - 1);
    const int iy0c = min(max(iy, 0), GH - 1);
    const int iy1c = min(max(iy + 1, 0), GH - 1);
    const int r0 = iy0c * (GW * 256) + cbase;
    const int r1 = iy1c * (GW * 256) + cbase;
    s8 g00 = *(const s8*)(vb + r0 + ix0c * 256);
    s8 g01 = *(const s8*)(vb + r0 + ix1c * 256);
    s8 g10 = *(const s8*)(vb + r1 + ix0c * 256);
    s8 g11 = *(const s8*)(vb + r1 + ix1c * 256);
    #pragma unroll
    for (int e = 0; e < 8; e++) {
      acc[e] += w00 * bf2f((unsigned short)g00[e]) + w01 * bf2f((unsigned short)g01[e])
              + w10 * bf2f((unsigned short)g10[e]) + w11 * bf2f((unsigned short)g11[e]);
    }
  }

  s8 res;
  #pragma unroll
  for (int e = 0; e < 8; e++) res[e] = f2bf(acc[e]);
  *(s8*)(o + (size_t)q * 256 + cbase) = res;
}

// --------------------------------------------------------------- launch ----
extern "C" void kernel_launch(void* const* d_in, const int* in_sizes, int n_in,
                              void* d_out, int out_size, void* d_ws, size_t ws_size,
                              hipStream_t stream)
{
  const float* query = (const float*)d_in[0];
  const float* value = (const float*)d_in[1];
  const float* refp  = (const float*)d_in[2];
  // d_in[3] spatial_shapes: compile-time (200,200)
  const float* Wv    = (const float*)d_in[4];
  const float* bv    = (const float*)d_in[5];
  const float* Woff  = (const float*)d_in[6];
  const float* boff  = (const float*)d_in[7];
  const float* Wattn = (const float*)d_in[8];
  const float* battn = (const float*)d_in[9];
  const float* Wo    = (const float*)d_in[10];
  const float* bo    = (const float*)d_in[11];

  char* ws = (char*)d_ws;
  unsigned short* ws_v = (unsigned short*)ws;                  // 80000*256 bf16 = 40.96 MB
  float*          ws_p = (float*)(ws + 40960000);              // 80000*128 f32  = 40.96 MB
  unsigned short* ws_o = (unsigned short*)(ws + 81920000);     // 80000*256 bf16 = 40.96 MB
  unsigned short* Wv_t = (unsigned short*)(ws + 122880000);    // 256*256 bf16
  unsigned short* Wo_t = Wv_t + 65536;                         // 256*256 bf16
  unsigned short* Wp_t = Wo_t + 65536;                         // 128*256 bf16
  float*          bp   = (float*)(Wp_t + 32768);               // 128 f32

  hipLaunchKernelGGL(prep_k, dim3(641), dim3(256), 0, stream,
                     Wv, Wo, Woff, Wattn, boff, battn, Wv_t, Wo_t, Wp_t, bp);
  // v = value @ Wv + bv  -> bf16
  hipLaunchKernelGGL((gemm_k<0, 1, 0>), dim3(625, 2), dim3(256), 0, stream,
                     (const void*)value, Wv_t, bv, (const float*)nullptr, (void*)ws_v, 256);
  // p = query @ [Woff|Wattn|0] + bp -> f32 (stride 128)
  hipLaunchKernelGGL((gemm_k<0, 0, 0>), dim3(625, 1), dim3(256), 0, stream,
                     (const void*)query, Wp_t, bp, (const float*)nullptr, (void*)ws_p, 128);
  // sampling
  hipLaunchKernelGGL(sample_k, dim3(10000), dim3(256), 0, stream,
                     ws_v, ws_p, refp, ws_o);
  // out = samp @ Wo + bo + query -> f32
  hipLaunchKernelGGL((gemm_k<1, 0, 1>), dim3(625, 2), dim3(256), 0, stream,
                     (const void*)ws_o, Wo_t, bo, query, (void*)d_out, 256);
}